// Round 1
// baseline (10996.345 us; speedup 1.0000x reference)
//
#include <hip/hip_runtime.h>
#include <math.h>

#define Tn 128
#define Bn 64
#define En 512
#define Hn 1024
#define Vn 10000
#define G4n 4096

// ---------------------------------------------------------------------------
// Tiled FP32 GEMM (NT): C[M,N] = A[M,K] @ B[N,K]^T + bias0 + bias1
// BM=BN=128, BK=16, 256 threads, 8x8 micro-tile. Optional row-gather on A.
// M must be a multiple of 128; N guarded.
// ---------------------------------------------------------------------------
__global__ __launch_bounds__(256) void gemm_nt_128(
    const int* __restrict__ gather, const float* __restrict__ A,
    const float* __restrict__ B, const float* __restrict__ bias0,
    const float* __restrict__ bias1, float* __restrict__ C,
    int M, int N, int K)
{
    __shared__ alignas(16) float As[16][132];  // [k][m], stride 132 (528B, 16B-aligned)
    __shared__ alignas(16) float Bs[16][132];  // [k][n]
    const int bm = blockIdx.x * 128;
    const int bn = blockIdx.y * 128;
    const int tid = threadIdx.x;
    const int tx = tid & 15;
    const int ty = tid >> 4;

    float acc[8][8];
#pragma unroll
    for (int i = 0; i < 8; ++i)
#pragma unroll
        for (int j = 0; j < 8; ++j) acc[i][j] = 0.f;

    for (int k0 = 0; k0 < K; k0 += 16) {
#pragma unroll
        for (int l = 0; l < 2; ++l) {
            const int slot = tid + l * 256;       // 512 float4 slots
            const int row  = slot >> 2;           // 128 rows, 4 float4 per row
            const int c4   = (slot & 3) << 2;
            const int ar = bm + row;
            const int sr = gather ? gather[ar] : ar;
            const float4 va = *(const float4*)(A + (size_t)sr * K + k0 + c4);
            As[c4 + 0][row] = va.x; As[c4 + 1][row] = va.y;
            As[c4 + 2][row] = va.z; As[c4 + 3][row] = va.w;
            const int br = bn + row;
            float4 vb = make_float4(0.f, 0.f, 0.f, 0.f);
            if (br < N) vb = *(const float4*)(B + (size_t)br * K + k0 + c4);
            Bs[c4 + 0][row] = vb.x; Bs[c4 + 1][row] = vb.y;
            Bs[c4 + 2][row] = vb.z; Bs[c4 + 3][row] = vb.w;
        }
        __syncthreads();
#pragma unroll
        for (int k = 0; k < 16; ++k) {
            const float4 a0 = *(const float4*)&As[k][(ty << 3) + 0];
            const float4 a1 = *(const float4*)&As[k][(ty << 3) + 4];
            const float4 b0 = *(const float4*)&Bs[k][(tx << 3) + 0];
            const float4 b1 = *(const float4*)&Bs[k][(tx << 3) + 4];
            const float a[8] = {a0.x, a0.y, a0.z, a0.w, a1.x, a1.y, a1.z, a1.w};
            const float b[8] = {b0.x, b0.y, b0.z, b0.w, b1.x, b1.y, b1.z, b1.w};
#pragma unroll
            for (int i = 0; i < 8; ++i)
#pragma unroll
                for (int j = 0; j < 8; ++j)
                    acc[i][j] = fmaf(a[i], b[j], acc[i][j]);
        }
        __syncthreads();
    }

#pragma unroll
    for (int i = 0; i < 8; ++i) {
        const int r = bm + (ty << 3) + i;
#pragma unroll
        for (int j = 0; j < 8; ++j) {
            const int cc = bn + (tx << 3) + j;
            if (cc < N) {
                float bv = 0.f;
                if (bias0) bv += bias0[cc];
                if (bias1) bv += bias1[cc];
                C[(size_t)r * N + cc] = acc[i][j] + bv;
            }
        }
    }
}

// ---------------------------------------------------------------------------
// One LSTM step: gates = xi_t + h_in @ W_hh^T ; cell update.
// Grid (64, 4): block owns hcols [bx*16, bx*16+16) x batches [by*16, by*16+16).
// Wave w (= tid>>6) computes gate w. Lane = (hc in 0..15) x (bsub in 0..3);
// each lane accumulates 4 batch rows (b = b0 + bsub*4 + a).
// No LDS staging for the GEMM: W_hh rows and h rows stream as float4-over-K
// (W_hh is 16 MB -> L2-resident across steps; h is 256 KB -> L1/L2).
// ---------------------------------------------------------------------------
__global__ __launch_bounds__(256) void lstm_step(
    const float* __restrict__ h_in, float* __restrict__ h_out,
    float* __restrict__ c, const float* __restrict__ W_hh,
    const float* __restrict__ xi_t, float* __restrict__ hs_t)
{
    const int tid  = threadIdx.x;
    const int lane = tid & 63;
    const int gate = tid >> 6;
    const int hc   = lane & 15;
    const int bsub = lane >> 4;
    const int hc0  = blockIdx.x << 4;
    const int b0   = blockIdx.y << 4;

    const float* wrow = W_hh + ((size_t)gate * Hn + hc0 + hc) * Hn;
    const float* h0p  = h_in + (size_t)(b0 + bsub * 4 + 0) * Hn;
    const float* h1p  = h_in + (size_t)(b0 + bsub * 4 + 1) * Hn;
    const float* h2p  = h_in + (size_t)(b0 + bsub * 4 + 2) * Hn;
    const float* h3p  = h_in + (size_t)(b0 + bsub * 4 + 3) * Hn;

    float acc0 = 0.f, acc1 = 0.f, acc2 = 0.f, acc3 = 0.f;
#pragma unroll 4
    for (int k = 0; k < Hn; k += 4) {
        const float4 wv = *(const float4*)(wrow + k);
        const float4 va = *(const float4*)(h0p + k);
        const float4 vb = *(const float4*)(h1p + k);
        const float4 vc = *(const float4*)(h2p + k);
        const float4 vd = *(const float4*)(h3p + k);
        acc0 = fmaf(va.x, wv.x, fmaf(va.y, wv.y, fmaf(va.z, wv.z, fmaf(va.w, wv.w, acc0))));
        acc1 = fmaf(vb.x, wv.x, fmaf(vb.y, wv.y, fmaf(vb.z, wv.z, fmaf(vb.w, wv.w, acc1))));
        acc2 = fmaf(vc.x, wv.x, fmaf(vc.y, wv.y, fmaf(vc.z, wv.z, fmaf(vc.w, wv.w, acc2))));
        acc3 = fmaf(vd.x, wv.x, fmaf(vd.y, wv.y, fmaf(vd.z, wv.z, fmaf(vd.w, wv.w, acc3))));
    }

    __shared__ float gls[4][16][16];   // [gate][hc][b_local], 4 KB
    gls[gate][hc][bsub * 4 + 0] = acc0;
    gls[gate][hc][bsub * 4 + 1] = acc1;
    gls[gate][hc][bsub * 4 + 2] = acc2;
    gls[gate][hc][bsub * 4 + 3] = acc3;
    __syncthreads();

    // cell update: one (b_local, hc) per thread
    const int hc2 = tid & 15;
    const int bl  = tid >> 4;
    const size_t xbase = (size_t)(b0 + bl) * G4n + hc0 + hc2;
    const float gi = gls[0][hc2][bl] + xi_t[xbase + 0 * Hn];
    const float gf = gls[1][hc2][bl] + xi_t[xbase + 1 * Hn];
    const float gg = gls[2][hc2][bl] + xi_t[xbase + 2 * Hn];
    const float go = gls[3][hc2][bl] + xi_t[xbase + 3 * Hn];
    const float is = 1.f / (1.f + expf(-gi));
    const float fs = 1.f / (1.f + expf(-gf));
    const float gt = tanhf(gg);
    const float os = 1.f / (1.f + expf(-go));
    const size_t cidx = (size_t)(b0 + bl) * Hn + hc0 + hc2;
    const float cn = fs * c[cidx] + is * gt;
    const float hn = os * tanhf(cn);
    c[cidx]     = cn;
    h_out[cidx] = hn;
    hs_t[cidx]  = hn;
}

// ---------------------------------------------------------------------------
// argmax over V per row (first occurrence on ties, matching jnp.argmax).
// row = t*B + b ; writes y[b*T + t] as float.
// ---------------------------------------------------------------------------
__global__ __launch_bounds__(256) void argmax_rows(
    const float* __restrict__ logits, float* __restrict__ y)
{
    const int row = blockIdx.x;
    const float* p = logits + (size_t)row * Vn;
    const int tid = threadIdx.x;
    float best = -INFINITY;
    int bi = Vn;
    for (int v = tid; v < Vn; v += 256) {
        const float x = p[v];
        if (x > best) { best = x; bi = v; }   // ascending scan -> first occurrence
    }
    __shared__ float sv[256];
    __shared__ int   si[256];
    sv[tid] = best; si[tid] = bi;
    __syncthreads();
    for (int s = 128; s > 0; s >>= 1) {
        if (tid < s) {
            const float ov = sv[tid + s];
            const int   oi = si[tid + s];
            if (ov > sv[tid] || (ov == sv[tid] && oi < si[tid])) {
                sv[tid] = ov; si[tid] = oi;
            }
        }
        __syncthreads();
    }
    if (tid == 0) {
        const int t = row >> 6;   // row = t*64 + b
        const int b = row & 63;
        y[(size_t)b * Tn + t] = (float)si[0];
    }
}

// ---------------------------------------------------------------------------
extern "C" void kernel_launch(void* const* d_in, const int* in_sizes, int n_in,
                              void* d_out, int out_size, void* d_ws, size_t ws_size,
                              hipStream_t stream)
{
    const int*   x      = (const int*)  d_in[0];   // (T,B) token ids
    // d_in[1] = lens : unused by the reference computation
    const float* emb    = (const float*)d_in[2];   // (V,E)
    const float* W_ih   = (const float*)d_in[3];   // (4H,E)
    const float* W_hh   = (const float*)d_in[4];   // (4H,H)
    const float* b_ih   = (const float*)d_in[5];   // (4H,)
    const float* b_hh   = (const float*)d_in[6];   // (4H,)
    const float* W_proj = (const float*)d_in[7];   // (V,H)
    const float* b_proj = (const float*)d_in[8];   // (V,)
    const float* h0     = (const float*)d_in[9];   // (B,H)
    const float* c0     = (const float*)d_in[10];  // (B,H)

    float* out    = (float*)d_out;
    float* logits = out;                           // (T,B,V)
    float* ypred  = out + (size_t)Tn * Bn * Vn;    // (B,T)

    float* ws  = (float*)d_ws;
    float* xi  = ws;                               // (T*B, 4H) = 134.2 MB
    float* hs  = xi  + (size_t)Tn * Bn * G4n;      // (T*B, H)  =  33.6 MB
    float* hb0 = hs  + (size_t)Tn * Bn * Hn;       // (B,H)
    float* hb1 = hb0 + (size_t)Bn * Hn;            // (B,H)
    float* cb  = hb1 + (size_t)Bn * Hn;            // (B,H)

    hipMemcpyAsync(hb0, h0, sizeof(float) * Bn * Hn, hipMemcpyDeviceToDevice, stream);
    hipMemcpyAsync(cb,  c0, sizeof(float) * Bn * Hn, hipMemcpyDeviceToDevice, stream);

    // xi = emb[x] @ W_ih^T + (b_ih + b_hh)
    {
        dim3 g(Tn * Bn / 128, G4n / 128);
        gemm_nt_128<<<g, 256, 0, stream>>>(x, emb, W_ih, b_ih, b_hh, xi,
                                           Tn * Bn, G4n, En);
    }

    // sequential recurrence
    for (int t = 0; t < Tn; ++t) {
        const float* hin = (t & 1) ? hb1 : hb0;
        float*       hout = (t & 1) ? hb0 : hb1;
        dim3 g(Hn / 16, Bn / 16);
        lstm_step<<<g, 256, 0, stream>>>(hin, hout, cb, W_hh,
                                         xi + (size_t)t * Bn * G4n,
                                         hs + (size_t)t * Bn * Hn);
    }

    // logits = hs @ W_proj^T + b_proj
    {
        dim3 g(Tn * Bn / 128, (Vn + 127) / 128);
        gemm_nt_128<<<g, 256, 0, stream>>>(nullptr, hs, W_proj, b_proj, nullptr,
                                           logits, Tn * Bn, Vn, Hn);
    }

    argmax_rows<<<Tn * Bn, 256, 0, stream>>>(logits, ypred);
}

// Round 2
// 10647.980 us; speedup vs baseline: 1.0327x; 1.0327x over previous
//
#include <hip/hip_runtime.h>
#include <math.h>

#define Tn 128
#define Bn 64
#define En 512
#define Hn 1024
#define Vn 10000
#define G4n 4096

// ---------------------------------------------------------------------------
// Tiled FP32 GEMM (NT): C[M,N] = A[M,K] @ B[N,K]^T + bias0 + bias1
// BM=BN=128, BK=16, 256 threads, 8x8 micro-tile held as two 4-wide halves
// (cols tx*4..+3 and 64+tx*4..+3) so LDS fragment reads are 2-way max (free).
// ---------------------------------------------------------------------------
__global__ __launch_bounds__(256) void gemm_nt_128(
    const int* __restrict__ gather, const float* __restrict__ A,
    const float* __restrict__ B, const float* __restrict__ bias0,
    const float* __restrict__ bias1, float* __restrict__ C,
    int M, int N, int K)
{
    __shared__ alignas(16) float As[16][132];
    __shared__ alignas(16) float Bs[16][132];
    const int bm = blockIdx.x * 128;
    const int bn = blockIdx.y * 128;
    const int tid = threadIdx.x;
    const int tx = tid & 15;
    const int ty = tid >> 4;

    float acc[8][8];
#pragma unroll
    for (int i = 0; i < 8; ++i)
#pragma unroll
        for (int j = 0; j < 8; ++j) acc[i][j] = 0.f;

    for (int k0 = 0; k0 < K; k0 += 16) {
#pragma unroll
        for (int l = 0; l < 2; ++l) {
            const int slot = tid + l * 256;
            const int row  = slot >> 2;
            const int c4   = (slot & 3) << 2;
            const int ar = bm + row;
            const int sr = gather ? gather[ar] : ar;
            const float4 va = *(const float4*)(A + (size_t)sr * K + k0 + c4);
            As[c4 + 0][row] = va.x; As[c4 + 1][row] = va.y;
            As[c4 + 2][row] = va.z; As[c4 + 3][row] = va.w;
            const int br = bn + row;
            float4 vb = make_float4(0.f, 0.f, 0.f, 0.f);
            if (br < N) vb = *(const float4*)(B + (size_t)br * K + k0 + c4);
            Bs[c4 + 0][row] = vb.x; Bs[c4 + 1][row] = vb.y;
            Bs[c4 + 2][row] = vb.z; Bs[c4 + 3][row] = vb.w;
        }
        __syncthreads();
#pragma unroll
        for (int k = 0; k < 16; ++k) {
            const float4 a0 = *(const float4*)&As[k][ty * 4];
            const float4 a1 = *(const float4*)&As[k][64 + ty * 4];
            const float4 b0 = *(const float4*)&Bs[k][tx * 4];
            const float4 b1 = *(const float4*)&Bs[k][64 + tx * 4];
            const float a[8] = {a0.x, a0.y, a0.z, a0.w, a1.x, a1.y, a1.z, a1.w};
            const float b[8] = {b0.x, b0.y, b0.z, b0.w, b1.x, b1.y, b1.z, b1.w};
#pragma unroll
            for (int i = 0; i < 8; ++i)
#pragma unroll
                for (int j = 0; j < 8; ++j)
                    acc[i][j] = fmaf(a[i], b[j], acc[i][j]);
        }
        __syncthreads();
    }

#pragma unroll
    for (int i = 0; i < 8; ++i) {
        const int r = bm + ((i < 4) ? (ty * 4 + i) : (64 + ty * 4 + i - 4));
#pragma unroll
        for (int j = 0; j < 8; ++j) {
            const int cc = bn + ((j < 4) ? (tx * 4 + j) : (64 + tx * 4 + j - 4));
            if (cc < N) {
                float bv = 0.f;
                if (bias0) bv += bias0[cc];
                if (bias1) bv += bias1[cc];
                C[(size_t)r * N + cc] = acc[i][j] + bv;
            }
        }
    }
}

// ---------------------------------------------------------------------------
// 32x32 tiled transpose: out[C][R] = in[R][C]^T
// ---------------------------------------------------------------------------
__global__ __launch_bounds__(256) void transpose32(
    const float* __restrict__ in, float* __restrict__ out, int R, int C)
{
    __shared__ float tile[32][33];
    const int c0 = blockIdx.x * 32, r0 = blockIdx.y * 32;
    const int j = threadIdx.x & 31, i0 = threadIdx.x >> 5;
#pragma unroll
    for (int ii = 0; ii < 4; ++ii) {
        const int i = i0 * 4 + ii;
        tile[i][j] = in[(size_t)(r0 + i) * C + c0 + j];
    }
    __syncthreads();
#pragma unroll
    for (int ii = 0; ii < 4; ++ii) {
        const int i = i0 * 4 + ii;
        out[(size_t)(c0 + i) * R + r0 + j] = tile[j][i];
    }
}

// ---------------------------------------------------------------------------
// Fused LSTM step. Grid 512 = (hg 16) x (gate 4) x (kc 8).
// Block: partial gates[64b x 64c] over k-chunk of 128, atomicAdd into xi[t]
// (pre-initialized with input GEMM + biases). Last block per hgroup (atomic
// counter == 31) performs the cell update for its 64 h-columns.
// hT: k-major hidden state [2][1024][64], double-buffered across steps.
// ---------------------------------------------------------------------------
__global__ __launch_bounds__(256, 2) void lstm_step_fused(
    const float* __restrict__ W_hh,   // [4096][1024]
    float* __restrict__ hT,           // [2][1024][64]
    float* __restrict__ cbuf,         // [64][1024]
    float* __restrict__ xi,           // [128][64][4096]
    float* __restrict__ hs,           // [128][64][1024]
    int* __restrict__ cnt, int t)
{
    __shared__ alignas(16) float smem[8448];   // 33 KB
    float* Wl = smem;          // [64 c][68 k-padded]
    float* hl = smem + 4352;   // [64 k][64 b]

    const int tid  = threadIdx.x;
    const int bid  = blockIdx.x;
    const int hg   = bid & 15;
    const int gate = (bid >> 4) & 3;
    const int kc   = bid >> 6;              // 0..7
    const int c0   = gate * Hn + hg * 64;
    const int k0   = kc * 128;
    const float* hTt = hT + (size_t)(t & 1) * Hn * Bn;

    const int bg = tid & 15;                // batch group (4 rows)
    const int cg = tid >> 4;                // col group (4 cols)

    float acc[4][4];
#pragma unroll
    for (int i = 0; i < 4; ++i)
#pragma unroll
        for (int j = 0; j < 4; ++j) acc[i][j] = 0.f;

    for (int sub = 0; sub < 2; ++sub) {
        const int kk = k0 + sub * 64;
        __syncthreads();
#pragma unroll
        for (int j = 0; j < 4; ++j) {
            const int slot = j * 256 + tid;      // 1024 slots = 64 rows x 16 f4
            const int row  = slot >> 4;
            const int q4   = (slot & 15) << 2;
            // W: row=c (c-major), coalesced along k
            *(float4*)&Wl[row * 68 + q4] =
                *(const float4*)&W_hh[(size_t)(c0 + row) * Hn + kk + q4];
            // h: row=k (k-major), coalesced along b
            *(float4*)&hl[row * 64 + q4] =
                *(const float4*)&hTt[(size_t)(kk + row) * Bn + q4];
        }
        __syncthreads();
#pragma unroll 4
        for (int k = 0; k < 64; k += 4) {
            float wr[4][4], hr[4][4];
#pragma unroll
            for (int j = 0; j < 4; ++j)
                *(float4*)wr[j] = *(const float4*)&Wl[(cg * 4 + j) * 68 + k];
#pragma unroll
            for (int dk = 0; dk < 4; ++dk)
                *(float4*)hr[dk] = *(const float4*)&hl[(k + dk) * 64 + bg * 4];
#pragma unroll
            for (int dk = 0; dk < 4; ++dk)
#pragma unroll
                for (int i = 0; i < 4; ++i)
#pragma unroll
                    for (int j = 0; j < 4; ++j)
                        acc[i][j] = fmaf(hr[dk][i], wr[j][dk], acc[i][j]);
        }
    }

    float* xit = xi + (size_t)t * Bn * G4n;
#pragma unroll
    for (int i = 0; i < 4; ++i) {
        const int b = bg * 4 + i;
#pragma unroll
        for (int j = 0; j < 4; ++j)
            atomicAdd(&xit[(size_t)b * G4n + c0 + cg * 4 + j], acc[i][j]);
    }
    __threadfence();

    __shared__ int lastFlag;
    if (tid == 0)
        lastFlag = (atomicAdd(&cnt[t * 16 + hg], 1) == 31) ? 1 : 0;
    __syncthreads();
    if (!lastFlag) return;
    __threadfence();

    // ---- cell update for hgroup hg: 64 hc x 64 b ----
    float* bounce = smem;                    // [64][65], fits in 33 KB
    float* hTn = hT + (size_t)((t + 1) & 1) * Hn * Bn;
    const int hcl = tid & 63;
    const int h   = hg * 64 + hcl;
#pragma unroll
    for (int i = 0; i < 16; ++i) {
        const int bb = i * 4 + (tid >> 6);
        const float* g = &xit[(size_t)bb * G4n + hg * 64 + hcl];
        const float gi = __hip_atomic_load(g + 0 * Hn, __ATOMIC_RELAXED, __HIP_MEMORY_SCOPE_AGENT);
        const float gf = __hip_atomic_load(g + 1 * Hn, __ATOMIC_RELAXED, __HIP_MEMORY_SCOPE_AGENT);
        const float gg = __hip_atomic_load(g + 2 * Hn, __ATOMIC_RELAXED, __HIP_MEMORY_SCOPE_AGENT);
        const float go = __hip_atomic_load(g + 3 * Hn, __ATOMIC_RELAXED, __HIP_MEMORY_SCOPE_AGENT);
        const float is = 1.f / (1.f + __expf(-gi));
        const float fs = 1.f / (1.f + __expf(-gf));
        const float e2 = __expf(2.f * gg);
        const float gt = 1.f - 2.f / (e2 + 1.f);
        const float os = 1.f / (1.f + __expf(-go));
        const float cold = cbuf[(size_t)bb * Hn + h];
        const float cn = fs * cold + is * gt;
        const float e2c = __expf(2.f * cn);
        const float hn = os * (1.f - 2.f / (e2c + 1.f));
        cbuf[(size_t)bb * Hn + h] = cn;
        hs[((size_t)t * Bn + bb) * Hn + h] = hn;
        bounce[hcl * 65 + bb] = hn;
    }
    __syncthreads();
#pragma unroll
    for (int i = 0; i < 16; ++i) {
        const int idx = i * 256 + tid;
        const int bb2 = idx & 63;
        const int hr  = idx >> 6;
        hTn[(size_t)(hg * 64 + hr) * Bn + bb2] = bounce[hr * 65 + bb2];
    }
}

// ---------------------------------------------------------------------------
// argmax over V per row (first occurrence on ties). row = t*B + b.
// ---------------------------------------------------------------------------
__global__ __launch_bounds__(256) void argmax_rows(
    const float* __restrict__ logits, float* __restrict__ y)
{
    const int row = blockIdx.x;
    const float* p = logits + (size_t)row * Vn;
    const int tid = threadIdx.x;
    float best = -INFINITY;
    int bi = Vn;
    for (int v = tid; v < Vn; v += 256) {
        const float x = p[v];
        if (x > best) { best = x; bi = v; }
    }
    __shared__ float sv[256];
    __shared__ int   si[256];
    sv[tid] = best; si[tid] = bi;
    __syncthreads();
    for (int s = 128; s > 0; s >>= 1) {
        if (tid < s) {
            const float ov = sv[tid + s];
            const int   oi = si[tid + s];
            if (ov > sv[tid] || (ov == sv[tid] && oi < si[tid])) {
                sv[tid] = ov; si[tid] = oi;
            }
        }
        __syncthreads();
    }
    if (tid == 0) {
        const int t = row >> 6;
        const int b = row & 63;
        y[(size_t)b * Tn + t] = (float)si[0];
    }
}

// ---------------------------------------------------------------------------
extern "C" void kernel_launch(void* const* d_in, const int* in_sizes, int n_in,
                              void* d_out, int out_size, void* d_ws, size_t ws_size,
                              hipStream_t stream)
{
    const int*   x      = (const int*)  d_in[0];
    const float* emb    = (const float*)d_in[2];
    const float* W_ih   = (const float*)d_in[3];
    const float* W_hh   = (const float*)d_in[4];
    const float* b_ih   = (const float*)d_in[5];
    const float* b_hh   = (const float*)d_in[6];
    const float* W_proj = (const float*)d_in[7];
    const float* b_proj = (const float*)d_in[8];
    const float* h0     = (const float*)d_in[9];
    const float* c0     = (const float*)d_in[10];

    float* out    = (float*)d_out;
    float* logits = out;                          // (T,B,V)
    float* ypred  = out + (size_t)Tn * Bn * Vn;   // (B,T)

    float* ws  = (float*)d_ws;
    float* xi  = ws;                              // (T*B, 4H)  134.2 MB
    float* hs  = xi  + (size_t)Tn * Bn * G4n;     // (T*B, H)    33.6 MB
    float* hT  = hs  + (size_t)Tn * Bn * Hn;      // [2][H][B]    0.5 MB
    float* cb  = hT  + (size_t)2 * Hn * Bn;       // [B][H]
    int*   cnt = (int*)(cb + (size_t)Bn * Hn);    // [128][16]

    hipMemcpyAsync(cb, c0, sizeof(float) * Bn * Hn, hipMemcpyDeviceToDevice, stream);
    hipMemsetAsync(cnt, 0, Tn * 16 * sizeof(int), stream);

    // hT[0] = h0^T  (B x H -> H x B)
    {
        dim3 g(Hn / 32, Bn / 32);
        transpose32<<<g, 256, 0, stream>>>(h0, hT, Bn, Hn);
    }

    // xi = emb[x] @ W_ih^T + (b_ih + b_hh)
    {
        dim3 g(Tn * Bn / 128, G4n / 128);
        gemm_nt_128<<<g, 256, 0, stream>>>(x, emb, W_ih, b_ih, b_hh, xi,
                                           Tn * Bn, G4n, En);
    }

    // recurrence: one fused kernel per step
    for (int t = 0; t < Tn; ++t)
        lstm_step_fused<<<512, 256, 0, stream>>>(W_hh, hT, cb, xi, hs, cnt, t);

    // logits = hs @ W_proj^T + b_proj
    {
        dim3 g(Tn * Bn / 128, (Vn + 127) / 128);
        gemm_nt_128<<<g, 256, 0, stream>>>(nullptr, hs, W_proj, b_proj, nullptr,
                                           logits, Tn * Bn, Vn, Hn);
    }

    argmax_rows<<<Tn * Bn, 256, 0, stream>>>(logits, ypred);
}